// Round 4
// baseline (623.326 us; speedup 1.0000x reference)
//
#include <hip/hip_runtime.h>
#include <hip/hip_fp16.h>
#include <math.h>

#define N_NODES 50000
#define N_EDGES 800000
#define D 128
#define L 3
#define SLOPE 0.2f
#define LN_EPS 1e-5f
#define ETOT (N_EDGES + N_NODES)
#define SCAN_BLOCKS ((N_NODES + 1023) / 1024)   // 49

typedef _Float16 half8 __attribute__((ext_vector_type(8)));
typedef _Float16 h4v  __attribute__((ext_vector_type(4)));
typedef _Float16 h2v  __attribute__((ext_vector_type(2)));
typedef float f32x4 __attribute__((ext_vector_type(4)));

// ---------------- CSR build (once per call, reused for all layers) ----------

__global__ void rank_hist_kernel(const int* __restrict__ ei, int* __restrict__ counts,
                                 int* __restrict__ rank) {
    int idx = blockIdx.x * blockDim.x + threadIdx.x;
    if (idx >= ETOT) return;
    int d = (idx < N_EDGES) ? ei[N_EDGES + idx] : (idx - N_EDGES);
    rank[idx] = atomicAdd(&counts[d], 1);
}

__global__ __launch_bounds__(1024) void scan1_kernel(const int* __restrict__ counts,
                                                     int* __restrict__ offsets,
                                                     int* __restrict__ bsum) {
    __shared__ int wsum[16];
    int tid = threadIdx.x;
    int lane = tid & 63, w = tid >> 6;
    int i = blockIdx.x * 1024 + tid;
    int v = (i < N_NODES) ? counts[i] : 0;
    int sc = v;
    #pragma unroll
    for (int off = 1; off < 64; off <<= 1) {
        int u = __shfl_up(sc, off);
        if (lane >= off) sc += u;
    }
    if (lane == 63) wsum[w] = sc;
    __syncthreads();
    if (w == 0) {
        int t2 = (lane < 16) ? wsum[lane] : 0;
        #pragma unroll
        for (int off = 1; off < 16; off <<= 1) {
            int u = __shfl_up(t2, off);
            if (lane >= off) t2 += u;
        }
        if (lane < 16) wsum[lane] = t2;
    }
    __syncthreads();
    int wpref = (w == 0) ? 0 : wsum[w - 1];
    if (i < N_NODES) offsets[i] = wpref + sc - v;      // block-local exclusive
    if (tid == 0) bsum[blockIdx.x] = wsum[15];
}

__global__ __launch_bounds__(64) void scan2_kernel(const int* __restrict__ bsum,
                                                   int* __restrict__ bpre) {
    int lane = threadIdx.x;
    int v = (lane < SCAN_BLOCKS) ? bsum[lane] : 0;
    int sc = v;
    #pragma unroll
    for (int off = 1; off < 64; off <<= 1) {
        int u = __shfl_up(sc, off);
        if (lane >= off) sc += u;
    }
    if (lane < SCAN_BLOCKS) bpre[lane] = sc - v;       // exclusive
}

__global__ __launch_bounds__(1024) void scan3_kernel(int* __restrict__ offsets,
                                                     const int* __restrict__ bpre) {
    int i = blockIdx.x * 1024 + threadIdx.x;
    if (i < N_NODES) offsets[i] += bpre[blockIdx.x];
    if (i == 0) offsets[N_NODES] = ETOT;
}

__global__ void scatter_kernel(const int* __restrict__ ei, const int* __restrict__ offsets,
                               const int* __restrict__ rank,
                               unsigned short* __restrict__ sorted16) {
    int idx = blockIdx.x * blockDim.x + threadIdx.x;
    if (idx >= ETOT) return;
    int s, d;
    if (idx < N_EDGES) { s = ei[idx]; d = ei[N_EDGES + idx]; }
    else               { s = d = idx - N_EDGES; }
    sorted16[offsets[d] + rank[idx]] = (unsigned short)s;   // no atomic
}

// ---------------- degree-sort permutation (counting sort, 256 bins) --------
// Groups nodes of equal/similar degree so each 4-node wave has ~zero masked
// waste in gat_node. perm is a permutation of 0..N-1 regardless of clamping.

__global__ void deg_hist_kernel(const int* __restrict__ counts, int* __restrict__ hist) {
    int i = blockIdx.x * blockDim.x + threadIdx.x;
    if (i >= N_NODES) return;
    int d = counts[i]; if (d > 255) d = 255;
    atomicAdd(&hist[d], 1);
}

__global__ __launch_bounds__(64) void deg_scan_kernel(const int* __restrict__ hist,
                                                      int* __restrict__ histoff) {
    int lane = threadIdx.x;                 // 64 lanes x 4 bins = 256 bins
    int4 v = ((const int4*)hist)[lane];
    int t = v.x + v.y + v.z + v.w;
    int sc = t;
    #pragma unroll
    for (int off = 1; off < 64; off <<= 1) {
        int u = __shfl_up(sc, off);
        if (lane >= off) sc += u;
    }
    int base = sc - t;                      // exclusive over 4-bin groups
    int4 o;
    o.x = base;
    o.y = base + v.x;
    o.z = base + v.x + v.y;
    o.w = base + v.x + v.y + v.z;
    ((int4*)histoff)[lane] = o;
}

__global__ void deg_scatter_kernel(const int* __restrict__ counts, int* __restrict__ histoff,
                                   int* __restrict__ perm) {
    int i = blockIdx.x * blockDim.x + threadIdx.x;
    if (i >= N_NODES) return;
    int d = counts[i]; if (d > 255) d = 255;
    int pos = atomicAdd(&histoff[d], 1);
    perm[pos] = i;
}

// ---------------- W -> fp16 MFMA B-fragment precompute ---------------------
// Wfrag[l][y][kt][nt][lane][j]; element = W[kt*32+(lane>>4)*8+j][nt*16+(lane&15)]

__global__ __launch_bounds__(256) void wfrag_kernel(const float* __restrict__ Wl,
                                                    const float* __restrict__ Wr,
                                                    _Float16* __restrict__ Wfrag) {
    int u = blockIdx.x * 256 + threadIdx.x;   // 3*2*4*8*64 = 12288 slots
    if (u >= 3 * 4096) return;
    int lane = u & 63, nt = (u >> 6) & 7, kt = (u >> 9) & 3, y = (u >> 11) & 1, l = u >> 12;
    int r = lane & 15, q = lane >> 4;
    const float* W = (y ? Wr : Wl) + (size_t)l * D * D;
    half8 v;
    #pragma unroll
    for (int j = 0; j < 8; ++j)
        v[j] = (_Float16)W[(kt * 32 + q * 8 + j) * D + nt * 16 + r];
    *(half8*)&Wfrag[(size_t)u * 8] = v;
}

// ---------------- MFMA GEMM: xl,xr (fp16) = h @ {Wl,Wr} --------------------
// block = 4 waves; tile M=64, N=256 (both W in one block -> h staged ONCE).

__global__ __launch_bounds__(256) void gemm_mfma_kernel(
        const float* __restrict__ h, const _Float16* __restrict__ WfragL,
        _Float16* __restrict__ xlh, _Float16* __restrict__ xrh) {
    __shared__ half8 Afrag[1024];   // [mt][kt][lane], 16 KB
    int t = threadIdx.x;
    int row0 = blockIdx.x * 64;
    {
        int kt = t >> 6, q = (t >> 4) & 3, r = t & 15;
        int kc = kt * 4 + q;                  // 8-half chunk index
        #pragma unroll
        for (int i = 0; i < 4; ++i) {
            int row = row0 + i * 16 + r;
            float4 f0 = make_float4(0.f, 0.f, 0.f, 0.f), f1 = f0;
            if (row < N_NODES) {
                const float* p = &h[(size_t)row * D + kc * 8];
                f0 = *(const float4*)p;
                f1 = *(const float4*)(p + 4);
            }
            half8 v;
            v[0] = (_Float16)f0.x; v[1] = (_Float16)f0.y;
            v[2] = (_Float16)f0.z; v[3] = (_Float16)f0.w;
            v[4] = (_Float16)f1.x; v[5] = (_Float16)f1.y;
            v[6] = (_Float16)f1.z; v[7] = (_Float16)f1.w;
            Afrag[i * 256 + t] = v;           // linear lanes: conflict-floor
        }
    }
    __syncthreads();
    int w = t >> 6, lane = t & 63;
    f32x4 acc[16];
    #pragma unroll
    for (int i = 0; i < 16; ++i) acc[i] = (f32x4){0.f, 0.f, 0.f, 0.f};
    #pragma unroll
    for (int kt = 0; kt < 4; ++kt) {
        half8 a = Afrag[(w * 4 + kt) * 64 + lane];
        #pragma unroll
        for (int y = 0; y < 2; ++y) {
            #pragma unroll
            for (int nt = 0; nt < 8; ++nt) {
                half8 b = *(const half8*)&WfragL[(size_t)(((y * 4 + kt) * 8 + nt) * 64 + lane) * 8];
                acc[y * 8 + nt] = __builtin_amdgcn_mfma_f32_16x16x32_f16(a, b, acc[y * 8 + nt], 0, 0, 0);
            }
        }
    }
    int rq = lane >> 4, rc = lane & 15;
    int rbase = row0 + w * 16 + rq * 4;       // C/D: col=lane&15, row=(lane>>4)*4+reg
    #pragma unroll
    for (int y = 0; y < 2; ++y) {
        _Float16* out = y ? xrh : xlh;
        #pragma unroll
        for (int nt = 0; nt < 8; ++nt) {
            #pragma unroll
            for (int reg = 0; reg < 4; ++reg) {
                int row = rbase + reg;
                if (row < N_NODES)
                    out[(size_t)row * D + nt * 16 + rc] = (_Float16)acc[y * 8 + nt][reg];
            }
        }
    }
}

// ---------------- per-node GATv2 + softmax + LN + ELU + residual -----------
// FOUR nodes per wave (degree-sorted so the 4 degrees are ~equal).
// 16 lanes per node, 8 channels per lane; head = 16 ch = 2 lanes -> single
// DPP pair-swap reduction. One ds_bpermute broadcasts the edge offsets of
// all 4 groups at once; loads are 16 B dwordx4 per lane (full 256-B row per
// group). One exp per 4 edges.

__device__ __forceinline__ float pair_reduce2(float p) {
    int t;
    t = __builtin_amdgcn_update_dpp(0, __float_as_int(p), 0xB1, 0xF, 0xF, true);  // quad [1,0,3,2]
    p += __int_as_float(t);
    return p;
}

__device__ __forceinline__ float logit8(half8 v, half8 xr, const h2v* att4, h2v slope2) {
    float p = 0.f;
    #pragma unroll
    for (int i = 0; i < 4; ++i) {
        h2v a; a[0] = v[2 * i];  a[1] = v[2 * i + 1];
        h2v b; b[0] = xr[2 * i]; b[1] = xr[2 * i + 1];
        h2v f  = a + b;                                   // v_pk_add_f16
        h2v lf = __builtin_elementwise_max(f, f * slope2);
        p = __builtin_amdgcn_fdot2(lf, att4[i], p, false);
    }
    return p;
}

template<int KUN, bool MASK>
__device__ __forceinline__ void edge_block(
        int j, int idx_bp, unsigned off, unsigned laneoff, const char* xlb,
        half8 xr8, const h2v* att4, h2v slope2, int cnt,
        float& s, float* acc) {
    half8 vs[KUN];
    #pragma unroll
    for (int k = 0; k < KUN; ++k) {
        int o = __builtin_amdgcn_ds_bpermute(idx_bp + 4 * (j + k), (int)off);
        vs[k] = *(const half8*)(xlb + ((unsigned)o + laneoff));   // dwordx4
    }
    #pragma unroll
    for (int k = 0; k < KUN; ++k) {
        float p = logit8(vs[k], xr8, att4, slope2);
        p = pair_reduce2(p);
        float e = __builtin_amdgcn_exp2f(p);
        if (MASK) e = (j + k < cnt) ? e : 0.f;
        s += e;
        #pragma unroll
        for (int i = 0; i < 8; ++i)
            acc[i] = fmaf(e, (float)vs[k][i], acc[i]);            // v_fma_mix
    }
}

__global__ __launch_bounds__(256) void gat_node_kernel(
        const _Float16* __restrict__ xlh, const _Float16* __restrict__ xrh,
        const int* __restrict__ offsets, const unsigned short* __restrict__ sorted16,
        const int* __restrict__ perm,
        const float* __restrict__ att_l, const float* __restrict__ bias_l,
        const float* __restrict__ gamma_l, const float* __restrict__ beta_l,
        const float* __restrict__ hin, float* __restrict__ hout) {
    int wid = (blockIdx.x * blockDim.x + threadIdx.x) >> 6;   // wave id
    if (wid * 4 >= N_NODES) return;
    int lane = threadIdx.x & 63;
    int g = lane >> 4, hl = lane & 15;         // group (node select), sub-lane
    int node = perm[wid * 4 + g];              // N_NODES % 4 == 0 -> valid
    unsigned laneoff = hl * 16u;               // byte offset of this lane's 8 halves
    int idx_bp = g << 6;                       // bpermute byte base: lane 16*g

    half8 xr8 = *(const half8*)&xrh[(size_t)node * D + hl * 8];
    float4 af0 = *(const float4*)&att_l[hl * 8];
    float4 af1 = *(const float4*)&att_l[hl * 8 + 4];
    h2v att4[4], slope2;
    att4[0][0] = (_Float16)(af0.x * 1.44269504f);  // pre-scale by log2(e)
    att4[0][1] = (_Float16)(af0.y * 1.44269504f);
    att4[1][0] = (_Float16)(af0.z * 1.44269504f);
    att4[1][1] = (_Float16)(af0.w * 1.44269504f);
    att4[2][0] = (_Float16)(af1.x * 1.44269504f);
    att4[2][1] = (_Float16)(af1.y * 1.44269504f);
    att4[3][0] = (_Float16)(af1.z * 1.44269504f);
    att4[3][1] = (_Float16)(af1.w * 1.44269504f);
    slope2[0] = (_Float16)SLOPE;
    slope2[1] = (_Float16)SLOPE;

    int beg = offsets[node], end = offsets[node + 1];
    int deg = end - beg;                                     // uniform per group
    int d0 = __builtin_amdgcn_readlane(deg, 0);
    int d1 = __builtin_amdgcn_readlane(deg, 16);
    int d2 = __builtin_amdgcn_readlane(deg, 32);
    int d3 = __builtin_amdgcn_readlane(deg, 48);
    int m01 = d0 > d1 ? d0 : d1, m23 = d2 > d3 ? d2 : d3;
    int degMax = m01 > m23 ? m01 : m23;
    int n01 = d0 < d1 ? d0 : d1, n23 = d2 < d3 ? d2 : d3;
    int degMin = n01 < n23 ? n01 : n23;

    float s = 0.f;
    float acc[8] = {0.f, 0.f, 0.f, 0.f, 0.f, 0.f, 0.f, 0.f};
    const char* xlb = (const char*)xlh;

    for (int c0 = 0; c0 < degMax; c0 += 16) {
        int rem = deg - c0;
        int cnt = rem > 16 ? 16 : rem;                       // may be <=0 on short group
        int cl  = cnt > 0 ? (hl < cnt ? hl : cnt - 1) : 0;
        int pos = cnt > 0 ? beg + c0 + cl : beg;             // clamped, always in-bounds
        unsigned off = ((unsigned)sorted16[pos]) << 8;       // fp16 row byte offset
        int jmax = degMax - c0; if (jmax > 16) jmax = 16;
        int nfull = degMin - c0; if (nfull > 16) nfull = 16; if (nfull < 0) nfull = 0;
        int j = 0;
        for (; j + 8 <= nfull; j += 8)                       // unmasked fast path
            edge_block<8, false>(j, idx_bp, off, laneoff, xlb, xr8, att4, slope2,
                                 cnt, s, acc);
        for (; j + 4 <= nfull; j += 4)
            edge_block<4, false>(j, idx_bp, off, laneoff, xlb, xr8, att4, slope2,
                                 cnt, s, acc);
        for (; j + 4 <= jmax; j += 4)                        // masked mid
            edge_block<4, true>(j, idx_bp, off, laneoff, xlb, xr8, att4, slope2,
                                cnt, s, acc);
        for (; j < jmax; ++j)                                // masked scalar tail
            edge_block<1, true>(j, idx_bp, off, laneoff, xlb, xr8, att4, slope2,
                                cnt, s, acc);
    }

    float inv = 1.f / s;                 // every node has >=1 edge (self-loop)
    float4 b0 = *(const float4*)&bias_l[hl * 8];
    float4 b1 = *(const float4*)&bias_l[hl * 8 + 4];
    float o[8];
    o[0] = acc[0] * inv + b0.x; o[1] = acc[1] * inv + b0.y;
    o[2] = acc[2] * inv + b0.z; o[3] = acc[3] * inv + b0.w;
    o[4] = acc[4] * inv + b1.x; o[5] = acc[5] * inv + b1.y;
    o[6] = acc[6] * inv + b1.z; o[7] = acc[7] * inv + b1.w;
    float sum = ((o[0] + o[1]) + (o[2] + o[3])) + ((o[4] + o[5]) + (o[6] + o[7]));
    float sq  = ((o[0] * o[0] + o[1] * o[1]) + (o[2] * o[2] + o[3] * o[3]))
              + ((o[4] * o[4] + o[5] * o[5]) + (o[6] * o[6] + o[7] * o[7]));
    #pragma unroll
    for (int msk = 1; msk < 16; msk <<= 1) {   // stays inside the 16-lane group
        sum += __shfl_xor(sum, msk);
        sq  += __shfl_xor(sq, msk);
    }
    float mu   = sum * (1.f / 128.f);
    float var  = sq * (1.f / 128.f) - mu * mu;
    float rstd = rsqrtf(var + LN_EPS);
    float4 g0 = *(const float4*)&gamma_l[hl * 8];
    float4 g1 = *(const float4*)&gamma_l[hl * 8 + 4];
    float4 e0 = *(const float4*)&beta_l[hl * 8];
    float4 e1 = *(const float4*)&beta_l[hl * 8 + 4];
    float gam[8] = {g0.x, g0.y, g0.z, g0.w, g1.x, g1.y, g1.z, g1.w};
    float bet[8] = {e0.x, e0.y, e0.z, e0.w, e1.x, e1.y, e1.z, e1.w};
    size_t di = (size_t)node * D + hl * 8;
    float4 h0 = *(const float4*)&hin[di];
    float4 h1 = *(const float4*)&hin[di + 4];
    float hv[8] = {h0.x, h0.y, h0.z, h0.w, h1.x, h1.y, h1.z, h1.w};
    float y[8];
    #pragma unroll
    for (int i = 0; i < 8; ++i) {
        float t = (o[i] - mu) * rstd * gam[i] + bet[i];
        t = t > 0.f ? t : __expf(t) - 1.f;   // ELU (alpha=1)
        y[i] = hv[i] + t;
    }
    float4 w0 = make_float4(y[0], y[1], y[2], y[3]);
    float4 w1 = make_float4(y[4], y[5], y[6], y[7]);
    *(float4*)&hout[di]     = w0;
    *(float4*)&hout[di + 4] = w1;
}

// ---------------------------------------------------------------------------

extern "C" void kernel_launch(void* const* d_in, const int* in_sizes, int n_in,
                              void* d_out, int out_size, void* d_ws, size_t ws_size,
                              hipStream_t stream) {
    const float* x     = (const float*)d_in[0];
    const float* Wl    = (const float*)d_in[1];
    const float* Wr    = (const float*)d_in[2];
    const float* att   = (const float*)d_in[3];
    const float* bias  = (const float*)d_in[4];
    const float* gamma = (const float*)d_in[5];
    const float* beta  = (const float*)d_in[6];
    const int*   ei    = (const int*)d_in[7];
    float* h = (float*)d_out;

    char* ws = (char*)d_ws;
    _Float16* xlh = (_Float16*)ws;   ws += (size_t)N_NODES * D * sizeof(_Float16);
    _Float16* xrh = (_Float16*)ws;   ws += (size_t)N_NODES * D * sizeof(_Float16);
    _Float16* Wfrag = (_Float16*)ws; ws += (size_t)3 * 4096 * 8 * sizeof(_Float16);
    int* offsets = (int*)ws;         ws += (size_t)(N_NODES + 4) * sizeof(int);
    int* counts  = (int*)ws;         ws += (size_t)N_NODES * sizeof(int);
    int* bsum    = (int*)ws;         ws += 64 * sizeof(int);
    int* bpre    = (int*)ws;         ws += 64 * sizeof(int);
    int* hist    = (int*)ws;         ws += 256 * sizeof(int);
    int* histoff = (int*)ws;         ws += 256 * sizeof(int);
    int* perm    = (int*)ws;         ws += (size_t)N_NODES * sizeof(int);
    int* rank    = (int*)ws;         ws += (size_t)ETOT * sizeof(int);
    unsigned short* sorted16 = (unsigned short*)ws;   // ETOT u16

    // W fragments (all layers) + CSR by dst + degree-sort perm (shared by all layers)
    wfrag_kernel<<<48, 256, 0, stream>>>(Wl, Wr, Wfrag);
    (void)hipMemsetAsync(counts, 0, (size_t)N_NODES * sizeof(int), stream);
    (void)hipMemsetAsync(hist, 0, 256 * sizeof(int), stream);
    rank_hist_kernel<<<(ETOT + 255) / 256, 256, 0, stream>>>(ei, counts, rank);
    scan1_kernel<<<SCAN_BLOCKS, 1024, 0, stream>>>(counts, offsets, bsum);
    scan2_kernel<<<1, 64, 0, stream>>>(bsum, bpre);
    scan3_kernel<<<SCAN_BLOCKS, 1024, 0, stream>>>(offsets, bpre);
    scatter_kernel<<<(ETOT + 255) / 256, 256, 0, stream>>>(ei, offsets, rank, sorted16);
    deg_hist_kernel<<<(N_NODES + 255) / 256, 256, 0, stream>>>(counts, hist);
    deg_scan_kernel<<<1, 64, 0, stream>>>(hist, histoff);
    deg_scatter_kernel<<<(N_NODES + 255) / 256, 256, 0, stream>>>(counts, histoff, perm);

    int gat_waves  = (N_NODES + 3) / 4;                       // 4 nodes / wave
    int gat_blocks = (gat_waves * 64 + 255) / 256;            // 3125
    for (int l = 0; l < L; ++l) {
        const float* hin = (l == 0) ? x : h;
        gemm_mfma_kernel<<<(N_NODES + 63) / 64, 256, 0, stream>>>(
            hin, Wfrag + (size_t)l * 4096 * 8, xlh, xrh);
        gat_node_kernel<<<gat_blocks, 256, 0, stream>>>(
            xlh, xrh, offsets, sorted16, perm,
            att + (size_t)l * D, bias + (size_t)l * D,
            gamma + (size_t)l * D, beta + (size_t)l * D, hin, h);
    }
}

// Round 5
// 344.912 us; speedup vs baseline: 1.8072x; 1.8072x over previous
//
#include <hip/hip_runtime.h>
#include <hip/hip_fp16.h>
#include <math.h>

#define N_NODES 50000
#define N_EDGES 800000
#define D 128
#define L 3
#define SLOPE 0.2f
#define LN_EPS 1e-5f
#define ETOT (N_EDGES + N_NODES)
#define SCAN_BLOCKS ((N_NODES + 1023) / 1024)   // 49

typedef _Float16 half8 __attribute__((ext_vector_type(8)));
typedef _Float16 h4v  __attribute__((ext_vector_type(4)));
typedef _Float16 h2v  __attribute__((ext_vector_type(2)));
typedef float f32x4 __attribute__((ext_vector_type(4)));

// ---------------- CSR build (once per call, reused for all layers) ----------

__global__ void rank_hist_kernel(const int* __restrict__ ei, int* __restrict__ counts,
                                 int* __restrict__ rank) {
    int idx = blockIdx.x * blockDim.x + threadIdx.x;
    if (idx >= ETOT) return;
    int d = (idx < N_EDGES) ? ei[N_EDGES + idx] : (idx - N_EDGES);
    rank[idx] = atomicAdd(&counts[d], 1);
}

__global__ __launch_bounds__(1024) void scan1_kernel(const int* __restrict__ counts,
                                                     int* __restrict__ offsets,
                                                     int* __restrict__ bsum) {
    __shared__ int wsum[16];
    int tid = threadIdx.x;
    int lane = tid & 63, w = tid >> 6;
    int i = blockIdx.x * 1024 + tid;
    int v = (i < N_NODES) ? counts[i] : 0;
    int sc = v;
    #pragma unroll
    for (int off = 1; off < 64; off <<= 1) {
        int u = __shfl_up(sc, off);
        if (lane >= off) sc += u;
    }
    if (lane == 63) wsum[w] = sc;
    __syncthreads();
    if (w == 0) {
        int t2 = (lane < 16) ? wsum[lane] : 0;
        #pragma unroll
        for (int off = 1; off < 16; off <<= 1) {
            int u = __shfl_up(t2, off);
            if (lane >= off) t2 += u;
        }
        if (lane < 16) wsum[lane] = t2;
    }
    __syncthreads();
    int wpref = (w == 0) ? 0 : wsum[w - 1];
    if (i < N_NODES) offsets[i] = wpref + sc - v;      // block-local exclusive
    if (tid == 0) bsum[blockIdx.x] = wsum[15];
}

__global__ __launch_bounds__(64) void scan2_kernel(const int* __restrict__ bsum,
                                                   int* __restrict__ bpre) {
    int lane = threadIdx.x;
    int v = (lane < SCAN_BLOCKS) ? bsum[lane] : 0;
    int sc = v;
    #pragma unroll
    for (int off = 1; off < 64; off <<= 1) {
        int u = __shfl_up(sc, off);
        if (lane >= off) sc += u;
    }
    if (lane < SCAN_BLOCKS) bpre[lane] = sc - v;       // exclusive
}

__global__ __launch_bounds__(1024) void scan3_kernel(int* __restrict__ offsets,
                                                     const int* __restrict__ bpre) {
    int i = blockIdx.x * 1024 + threadIdx.x;
    if (i < N_NODES) offsets[i] += bpre[blockIdx.x];
    if (i == 0) offsets[N_NODES] = ETOT;
}

__global__ void scatter_kernel(const int* __restrict__ ei, const int* __restrict__ offsets,
                               const int* __restrict__ rank,
                               unsigned short* __restrict__ sorted16) {
    int idx = blockIdx.x * blockDim.x + threadIdx.x;
    if (idx >= ETOT) return;
    int s, d;
    if (idx < N_EDGES) { s = ei[idx]; d = ei[N_EDGES + idx]; }
    else               { s = d = idx - N_EDGES; }
    sorted16[offsets[d] + rank[idx]] = (unsigned short)s;   // no atomic
}

// ---------------- degree-sort permutation (block-privatized counting sort) --
// Round-4 lesson: 50k fetch-add atomics on 256 GLOBAL bins = ~150us of
// serialized L2 RMWs. Privatize per block: LDS histograms (49 blocks x 1024
// nodes), a tiny 49x256 two-level scan, then scatter with LDS-rank + global
// base. Zero contended global atomics; any within-bin order is a valid perm.

__global__ __launch_bounds__(1024) void deg_hist_kernel(const int* __restrict__ counts,
                                                        int* __restrict__ blockhist) {
    __shared__ int lh[256];
    int tid = threadIdx.x;
    if (tid < 256) lh[tid] = 0;
    __syncthreads();
    int i = blockIdx.x * 1024 + tid;
    if (i < N_NODES) {
        int d = counts[i]; if (d > 255) d = 255;
        atomicAdd(&lh[d], 1);                       // LDS atomic: ~4-way, cheap
    }
    __syncthreads();
    if (tid < 256) blockhist[blockIdx.x * 256 + tid] = lh[tid];
}

__global__ __launch_bounds__(256) void deg_scan_kernel(int* __restrict__ blockhist) {
    int d = threadIdx.x;                            // one thread per bin
    int run = 0;
    #pragma unroll 1
    for (int b = 0; b < SCAN_BLOCKS; ++b) {         // column exclusive prefix
        int c = blockhist[b * 256 + d];
        blockhist[b * 256 + d] = run;
        run += c;
    }
    // block-wide exclusive scan of the 256 bin totals (4 waves)
    __shared__ int wsum[4];
    int lane = d & 63, w = d >> 6;
    int sc = run;
    #pragma unroll
    for (int off = 1; off < 64; off <<= 1) {
        int u = __shfl_up(sc, off);
        if (lane >= off) sc += u;
    }
    if (lane == 63) wsum[w] = sc;
    __syncthreads();
    int wpre = 0;
    #pragma unroll
    for (int k = 0; k < 4; ++k) wpre += (k < w) ? wsum[k] : 0;
    int binbase = wpre + sc - run;                  // exclusive over bins
    #pragma unroll 1
    for (int b = 0; b < SCAN_BLOCKS; ++b)
        blockhist[b * 256 + d] += binbase;
}

__global__ __launch_bounds__(1024) void deg_scatter_kernel(const int* __restrict__ counts,
                                                           const int* __restrict__ blockhist,
                                                           int* __restrict__ perm) {
    __shared__ int lh[256];
    int tid = threadIdx.x;
    if (tid < 256) lh[tid] = 0;
    __syncthreads();
    int i = blockIdx.x * 1024 + tid;
    if (i >= N_NODES) return;
    int d = counts[i]; if (d > 255) d = 255;
    int r = atomicAdd(&lh[d], 1);                   // LDS rank within block+bin
    int pos = blockhist[blockIdx.x * 256 + d] + r;
    perm[pos] = i;
}

// ---------------- W -> fp16 MFMA B-fragment precompute ---------------------
// Wfrag[l][y][kt][nt][lane][j]; element = W[kt*32+(lane>>4)*8+j][nt*16+(lane&15)]

__global__ __launch_bounds__(256) void wfrag_kernel(const float* __restrict__ Wl,
                                                    const float* __restrict__ Wr,
                                                    _Float16* __restrict__ Wfrag) {
    int u = blockIdx.x * 256 + threadIdx.x;   // 3*2*4*8*64 = 12288 slots
    if (u >= 3 * 4096) return;
    int lane = u & 63, nt = (u >> 6) & 7, kt = (u >> 9) & 3, y = (u >> 11) & 1, l = u >> 12;
    int r = lane & 15, q = lane >> 4;
    const float* W = (y ? Wr : Wl) + (size_t)l * D * D;
    half8 v;
    #pragma unroll
    for (int j = 0; j < 8; ++j)
        v[j] = (_Float16)W[(kt * 32 + q * 8 + j) * D + nt * 16 + r];
    *(half8*)&Wfrag[(size_t)u * 8] = v;
}

// ---------------- MFMA GEMM: xl,xr (fp16) = h @ {Wl,Wr} --------------------
// block = 4 waves; tile M=64, N=256 (both W in one block -> h staged ONCE).

__global__ __launch_bounds__(256) void gemm_mfma_kernel(
        const float* __restrict__ h, const _Float16* __restrict__ WfragL,
        _Float16* __restrict__ xlh, _Float16* __restrict__ xrh) {
    __shared__ half8 Afrag[1024];   // [mt][kt][lane], 16 KB
    int t = threadIdx.x;
    int row0 = blockIdx.x * 64;
    {
        int kt = t >> 6, q = (t >> 4) & 3, r = t & 15;
        int kc = kt * 4 + q;                  // 8-half chunk index
        #pragma unroll
        for (int i = 0; i < 4; ++i) {
            int row = row0 + i * 16 + r;
            float4 f0 = make_float4(0.f, 0.f, 0.f, 0.f), f1 = f0;
            if (row < N_NODES) {
                const float* p = &h[(size_t)row * D + kc * 8];
                f0 = *(const float4*)p;
                f1 = *(const float4*)(p + 4);
            }
            half8 v;
            v[0] = (_Float16)f0.x; v[1] = (_Float16)f0.y;
            v[2] = (_Float16)f0.z; v[3] = (_Float16)f0.w;
            v[4] = (_Float16)f1.x; v[5] = (_Float16)f1.y;
            v[6] = (_Float16)f1.z; v[7] = (_Float16)f1.w;
            Afrag[i * 256 + t] = v;           // linear lanes: conflict-floor
        }
    }
    __syncthreads();
    int w = t >> 6, lane = t & 63;
    f32x4 acc[16];
    #pragma unroll
    for (int i = 0; i < 16; ++i) acc[i] = (f32x4){0.f, 0.f, 0.f, 0.f};
    #pragma unroll
    for (int kt = 0; kt < 4; ++kt) {
        half8 a = Afrag[(w * 4 + kt) * 64 + lane];
        #pragma unroll
        for (int y = 0; y < 2; ++y) {
            #pragma unroll
            for (int nt = 0; nt < 8; ++nt) {
                half8 b = *(const half8*)&WfragL[(size_t)(((y * 4 + kt) * 8 + nt) * 64 + lane) * 8];
                acc[y * 8 + nt] = __builtin_amdgcn_mfma_f32_16x16x32_f16(a, b, acc[y * 8 + nt], 0, 0, 0);
            }
        }
    }
    int rq = lane >> 4, rc = lane & 15;
    int rbase = row0 + w * 16 + rq * 4;       // C/D: col=lane&15, row=(lane>>4)*4+reg
    #pragma unroll
    for (int y = 0; y < 2; ++y) {
        _Float16* out = y ? xrh : xlh;
        #pragma unroll
        for (int nt = 0; nt < 8; ++nt) {
            #pragma unroll
            for (int reg = 0; reg < 4; ++reg) {
                int row = rbase + reg;
                if (row < N_NODES)
                    out[(size_t)row * D + nt * 16 + rc] = (_Float16)acc[y * 8 + nt][reg];
            }
        }
    }
}

// ---------------- per-node GATv2 + softmax + LN + ELU + residual -----------
// FOUR nodes per wave (degree-sorted so the 4 degrees are ~equal).
// 16 lanes per node, 8 channels per lane; head = 16 ch = 2 lanes -> single
// DPP pair-swap reduction. One ds_bpermute broadcasts the edge offsets of
// all 4 groups at once; loads are 16 B dwordx4 per lane (full 256-B row per
// group). One exp per 4 edges.

__device__ __forceinline__ float pair_reduce2(float p) {
    int t;
    t = __builtin_amdgcn_update_dpp(0, __float_as_int(p), 0xB1, 0xF, 0xF, true);  // quad [1,0,3,2]
    p += __int_as_float(t);
    return p;
}

__device__ __forceinline__ float logit8(half8 v, half8 xr, const h2v* att4, h2v slope2) {
    float p = 0.f;
    #pragma unroll
    for (int i = 0; i < 4; ++i) {
        h2v a; a[0] = v[2 * i];  a[1] = v[2 * i + 1];
        h2v b; b[0] = xr[2 * i]; b[1] = xr[2 * i + 1];
        h2v f  = a + b;                                   // v_pk_add_f16
        h2v lf = __builtin_elementwise_max(f, f * slope2);
        p = __builtin_amdgcn_fdot2(lf, att4[i], p, false);
    }
    return p;
}

template<int KUN, bool MASK>
__device__ __forceinline__ void edge_block(
        int j, int idx_bp, unsigned off, unsigned laneoff, const char* xlb,
        half8 xr8, const h2v* att4, h2v slope2, int cnt,
        float& s, float* acc) {
    half8 vs[KUN];
    #pragma unroll
    for (int k = 0; k < KUN; ++k) {
        int o = __builtin_amdgcn_ds_bpermute(idx_bp + 4 * (j + k), (int)off);
        vs[k] = *(const half8*)(xlb + ((unsigned)o + laneoff));   // dwordx4
    }
    #pragma unroll
    for (int k = 0; k < KUN; ++k) {
        float p = logit8(vs[k], xr8, att4, slope2);
        p = pair_reduce2(p);
        float e = __builtin_amdgcn_exp2f(p);
        if (MASK) e = (j + k < cnt) ? e : 0.f;
        s += e;
        #pragma unroll
        for (int i = 0; i < 8; ++i)
            acc[i] = fmaf(e, (float)vs[k][i], acc[i]);            // v_fma_mix
    }
}

__global__ __launch_bounds__(256) void gat_node_kernel(
        const _Float16* __restrict__ xlh, const _Float16* __restrict__ xrh,
        const int* __restrict__ offsets, const unsigned short* __restrict__ sorted16,
        const int* __restrict__ perm,
        const float* __restrict__ att_l, const float* __restrict__ bias_l,
        const float* __restrict__ gamma_l, const float* __restrict__ beta_l,
        const float* __restrict__ hin, float* __restrict__ hout) {
    int wid = (blockIdx.x * blockDim.x + threadIdx.x) >> 6;   // wave id
    if (wid * 4 >= N_NODES) return;
    int lane = threadIdx.x & 63;
    int g = lane >> 4, hl = lane & 15;         // group (node select), sub-lane
    int node = perm[wid * 4 + g];              // N_NODES % 4 == 0 -> valid
    unsigned laneoff = hl * 16u;               // byte offset of this lane's 8 halves
    int idx_bp = g << 6;                       // bpermute byte base: lane 16*g

    half8 xr8 = *(const half8*)&xrh[(size_t)node * D + hl * 8];
    float4 af0 = *(const float4*)&att_l[hl * 8];
    float4 af1 = *(const float4*)&att_l[hl * 8 + 4];
    h2v att4[4], slope2;
    att4[0][0] = (_Float16)(af0.x * 1.44269504f);  // pre-scale by log2(e)
    att4[0][1] = (_Float16)(af0.y * 1.44269504f);
    att4[1][0] = (_Float16)(af0.z * 1.44269504f);
    att4[1][1] = (_Float16)(af0.w * 1.44269504f);
    att4[2][0] = (_Float16)(af1.x * 1.44269504f);
    att4[2][1] = (_Float16)(af1.y * 1.44269504f);
    att4[3][0] = (_Float16)(af1.z * 1.44269504f);
    att4[3][1] = (_Float16)(af1.w * 1.44269504f);
    slope2[0] = (_Float16)SLOPE;
    slope2[1] = (_Float16)SLOPE;

    int beg = offsets[node], end = offsets[node + 1];
    int deg = end - beg;                                     // uniform per group
    int d0 = __builtin_amdgcn_readlane(deg, 0);
    int d1 = __builtin_amdgcn_readlane(deg, 16);
    int d2 = __builtin_amdgcn_readlane(deg, 32);
    int d3 = __builtin_amdgcn_readlane(deg, 48);
    int m01 = d0 > d1 ? d0 : d1, m23 = d2 > d3 ? d2 : d3;
    int degMax = m01 > m23 ? m01 : m23;
    int n01 = d0 < d1 ? d0 : d1, n23 = d2 < d3 ? d2 : d3;
    int degMin = n01 < n23 ? n01 : n23;

    float s = 0.f;
    float acc[8] = {0.f, 0.f, 0.f, 0.f, 0.f, 0.f, 0.f, 0.f};
    const char* xlb = (const char*)xlh;

    for (int c0 = 0; c0 < degMax; c0 += 16) {
        int rem = deg - c0;
        int cnt = rem > 16 ? 16 : rem;                       // may be <=0 on short group
        int cl  = cnt > 0 ? (hl < cnt ? hl : cnt - 1) : 0;
        int pos = cnt > 0 ? beg + c0 + cl : beg;             // clamped, always in-bounds
        unsigned off = ((unsigned)sorted16[pos]) << 8;       // fp16 row byte offset
        int jmax = degMax - c0; if (jmax > 16) jmax = 16;
        int nfull = degMin - c0; if (nfull > 16) nfull = 16; if (nfull < 0) nfull = 0;
        int j = 0;
        for (; j + 8 <= nfull; j += 8)                       // unmasked fast path
            edge_block<8, false>(j, idx_bp, off, laneoff, xlb, xr8, att4, slope2,
                                 cnt, s, acc);
        for (; j + 4 <= nfull; j += 4)
            edge_block<4, false>(j, idx_bp, off, laneoff, xlb, xr8, att4, slope2,
                                 cnt, s, acc);
        for (; j + 4 <= jmax; j += 4)                        // masked mid
            edge_block<4, true>(j, idx_bp, off, laneoff, xlb, xr8, att4, slope2,
                                cnt, s, acc);
        for (; j < jmax; ++j)                                // masked scalar tail
            edge_block<1, true>(j, idx_bp, off, laneoff, xlb, xr8, att4, slope2,
                                cnt, s, acc);
    }

    float inv = 1.f / s;                 // every node has >=1 edge (self-loop)
    float4 b0 = *(const float4*)&bias_l[hl * 8];
    float4 b1 = *(const float4*)&bias_l[hl * 8 + 4];
    float o[8];
    o[0] = acc[0] * inv + b0.x; o[1] = acc[1] * inv + b0.y;
    o[2] = acc[2] * inv + b0.z; o[3] = acc[3] * inv + b0.w;
    o[4] = acc[4] * inv + b1.x; o[5] = acc[5] * inv + b1.y;
    o[6] = acc[6] * inv + b1.z; o[7] = acc[7] * inv + b1.w;
    float sum = ((o[0] + o[1]) + (o[2] + o[3])) + ((o[4] + o[5]) + (o[6] + o[7]));
    float sq  = ((o[0] * o[0] + o[1] * o[1]) + (o[2] * o[2] + o[3] * o[3]))
              + ((o[4] * o[4] + o[5] * o[5]) + (o[6] * o[6] + o[7] * o[7]));
    #pragma unroll
    for (int msk = 1; msk < 16; msk <<= 1) {   // stays inside the 16-lane group
        sum += __shfl_xor(sum, msk);
        sq  += __shfl_xor(sq, msk);
    }
    float mu   = sum * (1.f / 128.f);
    float var  = sq * (1.f / 128.f) - mu * mu;
    float rstd = rsqrtf(var + LN_EPS);
    float4 g0 = *(const float4*)&gamma_l[hl * 8];
    float4 g1 = *(const float4*)&gamma_l[hl * 8 + 4];
    float4 e0 = *(const float4*)&beta_l[hl * 8];
    float4 e1 = *(const float4*)&beta_l[hl * 8 + 4];
    float gam[8] = {g0.x, g0.y, g0.z, g0.w, g1.x, g1.y, g1.z, g1.w};
    float bet[8] = {e0.x, e0.y, e0.z, e0.w, e1.x, e1.y, e1.z, e1.w};
    size_t di = (size_t)node * D + hl * 8;
    float4 h0 = *(const float4*)&hin[di];
    float4 h1 = *(const float4*)&hin[di + 4];
    float hv[8] = {h0.x, h0.y, h0.z, h0.w, h1.x, h1.y, h1.z, h1.w};
    float y[8];
    #pragma unroll
    for (int i = 0; i < 8; ++i) {
        float t = (o[i] - mu) * rstd * gam[i] + bet[i];
        t = t > 0.f ? t : __expf(t) - 1.f;   // ELU (alpha=1)
        y[i] = hv[i] + t;
    }
    float4 w0 = make_float4(y[0], y[1], y[2], y[3]);
    float4 w1 = make_float4(y[4], y[5], y[6], y[7]);
    *(float4*)&hout[di]     = w0;
    *(float4*)&hout[di + 4] = w1;
}

// ---------------------------------------------------------------------------

extern "C" void kernel_launch(void* const* d_in, const int* in_sizes, int n_in,
                              void* d_out, int out_size, void* d_ws, size_t ws_size,
                              hipStream_t stream) {
    const float* x     = (const float*)d_in[0];
    const float* Wl    = (const float*)d_in[1];
    const float* Wr    = (const float*)d_in[2];
    const float* att   = (const float*)d_in[3];
    const float* bias  = (const float*)d_in[4];
    const float* gamma = (const float*)d_in[5];
    const float* beta  = (const float*)d_in[6];
    const int*   ei    = (const int*)d_in[7];
    float* h = (float*)d_out;

    char* ws = (char*)d_ws;
    _Float16* xlh = (_Float16*)ws;   ws += (size_t)N_NODES * D * sizeof(_Float16);
    _Float16* xrh = (_Float16*)ws;   ws += (size_t)N_NODES * D * sizeof(_Float16);
    _Float16* Wfrag = (_Float16*)ws; ws += (size_t)3 * 4096 * 8 * sizeof(_Float16);
    int* offsets = (int*)ws;         ws += (size_t)(N_NODES + 4) * sizeof(int);
    int* counts  = (int*)ws;         ws += (size_t)N_NODES * sizeof(int);
    int* bsum    = (int*)ws;         ws += 64 * sizeof(int);
    int* bpre    = (int*)ws;         ws += 64 * sizeof(int);
    int* blockhist = (int*)ws;       ws += (size_t)SCAN_BLOCKS * 256 * sizeof(int);
    int* perm    = (int*)ws;         ws += (size_t)N_NODES * sizeof(int);
    int* rank    = (int*)ws;         ws += (size_t)ETOT * sizeof(int);
    unsigned short* sorted16 = (unsigned short*)ws;   // ETOT u16

    // W fragments (all layers) + CSR by dst + degree-sort perm (shared by all layers)
    wfrag_kernel<<<48, 256, 0, stream>>>(Wl, Wr, Wfrag);
    (void)hipMemsetAsync(counts, 0, (size_t)N_NODES * sizeof(int), stream);
    rank_hist_kernel<<<(ETOT + 255) / 256, 256, 0, stream>>>(ei, counts, rank);
    scan1_kernel<<<SCAN_BLOCKS, 1024, 0, stream>>>(counts, offsets, bsum);
    scan2_kernel<<<1, 64, 0, stream>>>(bsum, bpre);
    scan3_kernel<<<SCAN_BLOCKS, 1024, 0, stream>>>(offsets, bpre);
    scatter_kernel<<<(ETOT + 255) / 256, 256, 0, stream>>>(ei, offsets, rank, sorted16);
    deg_hist_kernel<<<SCAN_BLOCKS, 1024, 0, stream>>>(counts, blockhist);
    deg_scan_kernel<<<1, 256, 0, stream>>>(blockhist);
    deg_scatter_kernel<<<SCAN_BLOCKS, 1024, 0, stream>>>(counts, blockhist, perm);

    int gat_waves  = (N_NODES + 3) / 4;                       // 4 nodes / wave
    int gat_blocks = (gat_waves * 64 + 255) / 256;            // 3125
    for (int l = 0; l < L; ++l) {
        const float* hin = (l == 0) ? x : h;
        gemm_mfma_kernel<<<(N_NODES + 63) / 64, 256, 0, stream>>>(
            hin, Wfrag + (size_t)l * 4096 * 8, xlh, xrh);
        gat_node_kernel<<<gat_blocks, 256, 0, stream>>>(
            xlh, xrh, offsets, sorted16, perm,
            att + (size_t)l * D, bias + (size_t)l * D,
            gamma + (size_t)l * D, beta + (size_t)l * D, hin, h);
    }
}

// Round 6
// 323.064 us; speedup vs baseline: 1.9294x; 1.0676x over previous
//
#include <hip/hip_runtime.h>
#include <hip/hip_fp16.h>
#include <math.h>

#define N_NODES 50000
#define N_EDGES 800000
#define D 128
#define L 3
#define SLOPE 0.2f
#define LN_EPS 1e-5f
#define ETOT (N_EDGES + N_NODES)
#define SCAN_BLOCKS ((N_NODES + 1023) / 1024)   // 49

typedef _Float16 half8 __attribute__((ext_vector_type(8)));
typedef _Float16 h4v  __attribute__((ext_vector_type(4)));
typedef _Float16 h2v  __attribute__((ext_vector_type(2)));
typedef float f32x4 __attribute__((ext_vector_type(4)));

// ---------------- CSR build (once per call, reused for all layers) ----------

__global__ void rank_hist_kernel(const int* __restrict__ ei, int* __restrict__ counts,
                                 int* __restrict__ rank) {
    int idx = blockIdx.x * blockDim.x + threadIdx.x;
    if (idx >= ETOT) return;
    int d = (idx < N_EDGES) ? ei[N_EDGES + idx] : (idx - N_EDGES);
    rank[idx] = atomicAdd(&counts[d], 1);
}

__global__ __launch_bounds__(1024) void scan1_kernel(const int* __restrict__ counts,
                                                     int* __restrict__ offsets,
                                                     int* __restrict__ bsum) {
    __shared__ int wsum[16];
    int tid = threadIdx.x;
    int lane = tid & 63, w = tid >> 6;
    int i = blockIdx.x * 1024 + tid;
    int v = (i < N_NODES) ? counts[i] : 0;
    int sc = v;
    #pragma unroll
    for (int off = 1; off < 64; off <<= 1) {
        int u = __shfl_up(sc, off);
        if (lane >= off) sc += u;
    }
    if (lane == 63) wsum[w] = sc;
    __syncthreads();
    if (w == 0) {
        int t2 = (lane < 16) ? wsum[lane] : 0;
        #pragma unroll
        for (int off = 1; off < 16; off <<= 1) {
            int u = __shfl_up(t2, off);
            if (lane >= off) t2 += u;
        }
        if (lane < 16) wsum[lane] = t2;
    }
    __syncthreads();
    int wpref = (w == 0) ? 0 : wsum[w - 1];
    if (i < N_NODES) offsets[i] = wpref + sc - v;      // block-local exclusive
    if (tid == 0) bsum[blockIdx.x] = wsum[15];
}

__global__ __launch_bounds__(64) void scan2_kernel(const int* __restrict__ bsum,
                                                   int* __restrict__ bpre) {
    int lane = threadIdx.x;
    int v = (lane < SCAN_BLOCKS) ? bsum[lane] : 0;
    int sc = v;
    #pragma unroll
    for (int off = 1; off < 64; off <<= 1) {
        int u = __shfl_up(sc, off);
        if (lane >= off) sc += u;
    }
    if (lane < SCAN_BLOCKS) bpre[lane] = sc - v;       // exclusive
}

__global__ __launch_bounds__(1024) void scan3_kernel(int* __restrict__ offsets,
                                                     const int* __restrict__ bpre) {
    int i = blockIdx.x * 1024 + threadIdx.x;
    if (i < N_NODES) offsets[i] += bpre[blockIdx.x];
    if (i == 0) offsets[N_NODES] = ETOT;
}

__global__ void scatter_kernel(const int* __restrict__ ei, const int* __restrict__ offsets,
                               const int* __restrict__ rank,
                               unsigned short* __restrict__ sorted16) {
    int idx = blockIdx.x * blockDim.x + threadIdx.x;
    if (idx >= ETOT) return;
    int s, d;
    if (idx < N_EDGES) { s = ei[idx]; d = ei[N_EDGES + idx]; }
    else               { s = d = idx - N_EDGES; }
    sorted16[offsets[d] + rank[idx]] = (unsigned short)s;   // no atomic
}

// ---------------- degree-sort permutation (block-privatized counting sort) --

__global__ __launch_bounds__(1024) void deg_hist_kernel(const int* __restrict__ counts,
                                                        int* __restrict__ blockhist) {
    __shared__ int lh[256];
    int tid = threadIdx.x;
    if (tid < 256) lh[tid] = 0;
    __syncthreads();
    int i = blockIdx.x * 1024 + tid;
    if (i < N_NODES) {
        int d = counts[i]; if (d > 255) d = 255;
        atomicAdd(&lh[d], 1);                       // LDS atomic: cheap
    }
    __syncthreads();
    if (tid < 256) blockhist[blockIdx.x * 256 + tid] = lh[tid];
}

__global__ __launch_bounds__(256) void deg_scan_kernel(int* __restrict__ blockhist) {
    int d = threadIdx.x;                            // one thread per bin
    int run = 0;
    #pragma unroll 1
    for (int b = 0; b < SCAN_BLOCKS; ++b) {         // column exclusive prefix
        int c = blockhist[b * 256 + d];
        blockhist[b * 256 + d] = run;
        run += c;
    }
    __shared__ int wsum[4];
    int lane = d & 63, w = d >> 6;
    int sc = run;
    #pragma unroll
    for (int off = 1; off < 64; off <<= 1) {
        int u = __shfl_up(sc, off);
        if (lane >= off) sc += u;
    }
    if (lane == 63) wsum[w] = sc;
    __syncthreads();
    int wpre = 0;
    #pragma unroll
    for (int k = 0; k < 4; ++k) wpre += (k < w) ? wsum[k] : 0;
    int binbase = wpre + sc - run;                  // exclusive over bins
    #pragma unroll 1
    for (int b = 0; b < SCAN_BLOCKS; ++b)
        blockhist[b * 256 + d] += binbase;
}

__global__ __launch_bounds__(1024) void deg_scatter_kernel(const int* __restrict__ counts,
                                                           const int* __restrict__ blockhist,
                                                           int* __restrict__ perm) {
    __shared__ int lh[256];
    int tid = threadIdx.x;
    if (tid < 256) lh[tid] = 0;
    __syncthreads();
    int i = blockIdx.x * 1024 + tid;
    if (i >= N_NODES) return;
    int d = counts[i]; if (d > 255) d = 255;
    int r = atomicAdd(&lh[d], 1);                   // LDS rank within block+bin
    int pos = blockhist[blockIdx.x * 256 + d] + r;
    perm[pos] = i;
}

// ---------------- W -> fp16 MFMA B-fragment precompute ---------------------
// Wfrag[l][y][kt][nt][lane][j]; element = W[kt*32+(lane>>4)*8+j][nt*16+(lane&15)]

__global__ __launch_bounds__(256) void wfrag_kernel(const float* __restrict__ Wl,
                                                    const float* __restrict__ Wr,
                                                    _Float16* __restrict__ Wfrag) {
    int u = blockIdx.x * 256 + threadIdx.x;   // 3*2*4*8*64 = 12288 slots
    if (u >= 3 * 4096) return;
    int lane = u & 63, nt = (u >> 6) & 7, kt = (u >> 9) & 3, y = (u >> 11) & 1, l = u >> 12;
    int r = lane & 15, q = lane >> 4;
    const float* W = (y ? Wr : Wl) + (size_t)l * D * D;
    half8 v;
    #pragma unroll
    for (int j = 0; j < 8; ++j)
        v[j] = (_Float16)W[(kt * 32 + q * 8 + j) * D + nt * 16 + r];
    *(half8*)&Wfrag[(size_t)u * 8] = v;
}

// ---------------- MFMA GEMM: xl,xr (fp16) = h @ {Wl,Wr} --------------------
// block = 4 waves; tile M=64, N=256. NEW wave mapping: wave owns (y, col-half)
// -> its 16 B-fragments are loaded ONCE into registers (64 -> 16 B-loads/wave)
// and issued BEFORE the A staging so their L2 latency hides under the HBM
// staging reads. A comes from LDS per (mt,kt), reused across 4 nt MFMAs.

__global__ __launch_bounds__(256) void gemm_mfma_kernel(
        const float* __restrict__ h, const _Float16* __restrict__ WfragL,
        _Float16* __restrict__ xlh, _Float16* __restrict__ xrh) {
    __shared__ half8 Afrag[1024];   // [mt][kt][lane], 16 KB
    int t = threadIdx.x;
    int row0 = blockIdx.x * 64;
    int w = t >> 6, lane = t & 63;
    int y = w >> 1, nh = w & 1;     // wave's W-matrix (l/r) and column half

    // ---- B fragments: issue first (latency hidden under A staging) ----
    half8 bfrag[16];                // [kt][n], compile-time indexed only
    #pragma unroll
    for (int kt = 0; kt < 4; ++kt)
        #pragma unroll
        for (int n = 0; n < 4; ++n) {
            int nt = nh * 4 + n;
            bfrag[kt * 4 + n] =
                *(const half8*)&WfragL[(size_t)(((y * 4 + kt) * 8 + nt) * 64 + lane) * 8];
        }

    // ---- A staging: fp32 h tile -> fp16 fragments in LDS ----
    {
        int kt = t >> 6, q = (t >> 4) & 3, r = t & 15;
        int kc = kt * 4 + q;                  // 8-half chunk index
        #pragma unroll
        for (int i = 0; i < 4; ++i) {
            int row = row0 + i * 16 + r;
            float4 f0 = make_float4(0.f, 0.f, 0.f, 0.f), f1 = f0;
            if (row < N_NODES) {
                const float* p = &h[(size_t)row * D + kc * 8];
                f0 = *(const float4*)p;
                f1 = *(const float4*)(p + 4);
            }
            half8 v;
            v[0] = (_Float16)f0.x; v[1] = (_Float16)f0.y;
            v[2] = (_Float16)f0.z; v[3] = (_Float16)f0.w;
            v[4] = (_Float16)f1.x; v[5] = (_Float16)f1.y;
            v[6] = (_Float16)f1.z; v[7] = (_Float16)f1.w;
            Afrag[i * 256 + t] = v;           // [mt][kt*64 + q*16 + r]
        }
    }
    __syncthreads();

    // ---- compute: 4 mt x 4 kt x 4 nt MFMAs, B register-resident ----
    f32x4 acc[16];                  // [mt][n]
    #pragma unroll
    for (int i = 0; i < 16; ++i) acc[i] = (f32x4){0.f, 0.f, 0.f, 0.f};
    #pragma unroll
    for (int mt = 0; mt < 4; ++mt) {
        #pragma unroll
        for (int kt = 0; kt < 4; ++kt) {
            half8 a = Afrag[mt * 256 + kt * 64 + lane];
            #pragma unroll
            for (int n = 0; n < 4; ++n)
                acc[mt * 4 + n] = __builtin_amdgcn_mfma_f32_16x16x32_f16(
                    a, bfrag[kt * 4 + n], acc[mt * 4 + n], 0, 0, 0);
        }
    }

    // ---- store: wave writes its (y, col-half) slice for all 64 rows ----
    _Float16* out = y ? xrh : xlh;
    int rq = lane >> 4, rc = lane & 15;
    #pragma unroll
    for (int mt = 0; mt < 4; ++mt) {
        int rbase = row0 + mt * 16 + rq * 4;  // C/D: col=lane&15, row=(lane>>4)*4+reg
        #pragma unroll
        for (int n = 0; n < 4; ++n) {
            int nt = nh * 4 + n;
            #pragma unroll
            for (int reg = 0; reg < 4; ++reg) {
                int row = rbase + reg;
                if (row < N_NODES)
                    out[(size_t)row * D + nt * 16 + rc] = (_Float16)acc[mt * 4 + n][reg];
            }
        }
    }
}

// ---------------- per-node GATv2 + softmax + LN + ELU + residual -----------
// FOUR nodes per wave (degree-sorted so the 4 degrees are ~equal).
// 16 lanes per node, 8 channels per lane; head = 16 ch = 2 lanes -> single
// DPP pair-swap reduction. One ds_bpermute broadcasts the edge offsets of
// all 4 groups at once; loads are 16 B dwordx4 per lane.

__device__ __forceinline__ float pair_reduce2(float p) {
    int t;
    t = __builtin_amdgcn_update_dpp(0, __float_as_int(p), 0xB1, 0xF, 0xF, true);  // quad [1,0,3,2]
    p += __int_as_float(t);
    return p;
}

__device__ __forceinline__ float logit8(half8 v, half8 xr, const h2v* att4, h2v slope2) {
    float p = 0.f;
    #pragma unroll
    for (int i = 0; i < 4; ++i) {
        h2v a; a[0] = v[2 * i];  a[1] = v[2 * i + 1];
        h2v b; b[0] = xr[2 * i]; b[1] = xr[2 * i + 1];
        h2v f  = a + b;                                   // v_pk_add_f16
        h2v lf = __builtin_elementwise_max(f, f * slope2);
        p = __builtin_amdgcn_fdot2(lf, att4[i], p, false);
    }
    return p;
}

template<int KUN, bool MASK>
__device__ __forceinline__ void edge_block(
        int j, int idx_bp, unsigned off, unsigned laneoff, const char* xlb,
        half8 xr8, const h2v* att4, h2v slope2, int cnt,
        float& s, float* acc) {
    half8 vs[KUN];
    #pragma unroll
    for (int k = 0; k < KUN; ++k) {
        int o = __builtin_amdgcn_ds_bpermute(idx_bp + 4 * (j + k), (int)off);
        vs[k] = *(const half8*)(xlb + ((unsigned)o + laneoff));   // dwordx4
    }
    #pragma unroll
    for (int k = 0; k < KUN; ++k) {
        float p = logit8(vs[k], xr8, att4, slope2);
        p = pair_reduce2(p);
        float e = __builtin_amdgcn_exp2f(p);
        if (MASK) e = (j + k < cnt) ? e : 0.f;
        s += e;
        #pragma unroll
        for (int i = 0; i < 8; ++i)
            acc[i] = fmaf(e, (float)vs[k][i], acc[i]);            // v_fma_mix
    }
}

__global__ __launch_bounds__(256) void gat_node_kernel(
        const _Float16* __restrict__ xlh, const _Float16* __restrict__ xrh,
        const int* __restrict__ offsets, const unsigned short* __restrict__ sorted16,
        const int* __restrict__ perm,
        const float* __restrict__ att_l, const float* __restrict__ bias_l,
        const float* __restrict__ gamma_l, const float* __restrict__ beta_l,
        const float* __restrict__ hin, float* __restrict__ hout) {
    int wid = (blockIdx.x * blockDim.x + threadIdx.x) >> 6;   // wave id
    if (wid * 4 >= N_NODES) return;
    int lane = threadIdx.x & 63;
    int g = lane >> 4, hl = lane & 15;         // group (node select), sub-lane
    int node = perm[wid * 4 + g];              // N_NODES % 4 == 0 -> valid
    unsigned laneoff = hl * 16u;               // byte offset of this lane's 8 halves
    int idx_bp = g << 6;                       // bpermute byte base: lane 16*g

    half8 xr8 = *(const half8*)&xrh[(size_t)node * D + hl * 8];
    float4 af0 = *(const float4*)&att_l[hl * 8];
    float4 af1 = *(const float4*)&att_l[hl * 8 + 4];
    h2v att4[4], slope2;
    att4[0][0] = (_Float16)(af0.x * 1.44269504f);  // pre-scale by log2(e)
    att4[0][1] = (_Float16)(af0.y * 1.44269504f);
    att4[1][0] = (_Float16)(af0.z * 1.44269504f);
    att4[1][1] = (_Float16)(af0.w * 1.44269504f);
    att4[2][0] = (_Float16)(af1.x * 1.44269504f);
    att4[2][1] = (_Float16)(af1.y * 1.44269504f);
    att4[3][0] = (_Float16)(af1.z * 1.44269504f);
    att4[3][1] = (_Float16)(af1.w * 1.44269504f);
    slope2[0] = (_Float16)SLOPE;
    slope2[1] = (_Float16)SLOPE;

    int beg = offsets[node], end = offsets[node + 1];
    int deg = end - beg;                                     // uniform per group
    int d0 = __builtin_amdgcn_readlane(deg, 0);
    int d1 = __builtin_amdgcn_readlane(deg, 16);
    int d2 = __builtin_amdgcn_readlane(deg, 32);
    int d3 = __builtin_amdgcn_readlane(deg, 48);
    int m01 = d0 > d1 ? d0 : d1, m23 = d2 > d3 ? d2 : d3;
    int degMax = m01 > m23 ? m01 : m23;
    int n01 = d0 < d1 ? d0 : d1, n23 = d2 < d3 ? d2 : d3;
    int degMin = n01 < n23 ? n01 : n23;

    float s = 0.f;
    float acc[8] = {0.f, 0.f, 0.f, 0.f, 0.f, 0.f, 0.f, 0.f};
    const char* xlb = (const char*)xlh;

    for (int c0 = 0; c0 < degMax; c0 += 16) {
        int rem = deg - c0;
        int cnt = rem > 16 ? 16 : rem;                       // may be <=0 on short group
        int cl  = cnt > 0 ? (hl < cnt ? hl : cnt - 1) : 0;
        int pos = cnt > 0 ? beg + c0 + cl : beg;             // clamped, always in-bounds
        unsigned off = ((unsigned)sorted16[pos]) << 8;       // fp16 row byte offset
        int jmax = degMax - c0; if (jmax > 16) jmax = 16;
        int nfull = degMin - c0; if (nfull > 16) nfull = 16; if (nfull < 0) nfull = 0;
        int j = 0;
        for (; j + 8 <= nfull; j += 8)                       // unmasked fast path
            edge_block<8, false>(j, idx_bp, off, laneoff, xlb, xr8, att4, slope2,
                                 cnt, s, acc);
        for (; j + 4 <= nfull; j += 4)
            edge_block<4, false>(j, idx_bp, off, laneoff, xlb, xr8, att4, slope2,
                                 cnt, s, acc);
        for (; j + 4 <= jmax; j += 4)                        // masked mid
            edge_block<4, true>(j, idx_bp, off, laneoff, xlb, xr8, att4, slope2,
                                cnt, s, acc);
        for (; j < jmax; ++j)                                // masked scalar tail
            edge_block<1, true>(j, idx_bp, off, laneoff, xlb, xr8, att4, slope2,
                                cnt, s, acc);
    }

    float inv = 1.f / s;                 // every node has >=1 edge (self-loop)
    float4 b0 = *(const float4*)&bias_l[hl * 8];
    float4 b1 = *(const float4*)&bias_l[hl * 8 + 4];
    float o[8];
    o[0] = acc[0] * inv + b0.x; o[1] = acc[1] * inv + b0.y;
    o[2] = acc[2] * inv + b0.z; o[3] = acc[3] * inv + b0.w;
    o[4] = acc[4] * inv + b1.x; o[5] = acc[5] * inv + b1.y;
    o[6] = acc[6] * inv + b1.z; o[7] = acc[7] * inv + b1.w;
    float sum = ((o[0] + o[1]) + (o[2] + o[3])) + ((o[4] + o[5]) + (o[6] + o[7]));
    float sq  = ((o[0] * o[0] + o[1] * o[1]) + (o[2] * o[2] + o[3] * o[3]))
              + ((o[4] * o[4] + o[5] * o[5]) + (o[6] * o[6] + o[7] * o[7]));
    #pragma unroll
    for (int msk = 1; msk < 16; msk <<= 1) {   // stays inside the 16-lane group
        sum += __shfl_xor(sum, msk);
        sq  += __shfl_xor(sq, msk);
    }
    float mu   = sum * (1.f / 128.f);
    float var  = sq * (1.f / 128.f) - mu * mu;
    float rstd = rsqrtf(var + LN_EPS);
    float4 g0 = *(const float4*)&gamma_l[hl * 8];
    float4 g1 = *(const float4*)&gamma_l[hl * 8 + 4];
    float4 e0 = *(const float4*)&beta_l[hl * 8];
    float4 e1 = *(const float4*)&beta_l[hl * 8 + 4];
    float gam[8] = {g0.x, g0.y, g0.z, g0.w, g1.x, g1.y, g1.z, g1.w};
    float bet[8] = {e0.x, e0.y, e0.z, e0.w, e1.x, e1.y, e1.z, e1.w};
    size_t di = (size_t)node * D + hl * 8;
    float4 h0 = *(const float4*)&hin[di];
    float4 h1 = *(const float4*)&hin[di + 4];
    float hv[8] = {h0.x, h0.y, h0.z, h0.w, h1.x, h1.y, h1.z, h1.w};
    float y[8];
    #pragma unroll
    for (int i = 0; i < 8; ++i) {
        float t = (o[i] - mu) * rstd * gam[i] + bet[i];
        t = t > 0.f ? t : __expf(t) - 1.f;   // ELU (alpha=1)
        y[i] = hv[i] + t;
    }
    float4 w0 = make_float4(y[0], y[1], y[2], y[3]);
    float4 w1 = make_float4(y[4], y[5], y[6], y[7]);
    *(float4*)&hout[di]     = w0;
    *(float4*)&hout[di + 4] = w1;
}

// ---------------------------------------------------------------------------

extern "C" void kernel_launch(void* const* d_in, const int* in_sizes, int n_in,
                              void* d_out, int out_size, void* d_ws, size_t ws_size,
                              hipStream_t stream) {
    const float* x     = (const float*)d_in[0];
    const float* Wl    = (const float*)d_in[1];
    const float* Wr    = (const float*)d_in[2];
    const float* att   = (const float*)d_in[3];
    const float* bias  = (const float*)d_in[4];
    const float* gamma = (const float*)d_in[5];
    const float* beta  = (const float*)d_in[6];
    const int*   ei    = (const int*)d_in[7];
    float* h = (float*)d_out;

    char* ws = (char*)d_ws;
    _Float16* xlh = (_Float16*)ws;   ws += (size_t)N_NODES * D * sizeof(_Float16);
    _Float16* xrh = (_Float16*)ws;   ws += (size_t)N_NODES * D * sizeof(_Float16);
    _Float16* Wfrag = (_Float16*)ws; ws += (size_t)3 * 4096 * 8 * sizeof(_Float16);
    int* offsets = (int*)ws;         ws += (size_t)(N_NODES + 4) * sizeof(int);
    int* counts  = (int*)ws;         ws += (size_t)N_NODES * sizeof(int);
    int* bsum    = (int*)ws;         ws += 64 * sizeof(int);
    int* bpre    = (int*)ws;         ws += 64 * sizeof(int);
    int* blockhist = (int*)ws;       ws += (size_t)SCAN_BLOCKS * 256 * sizeof(int);
    int* perm    = (int*)ws;         ws += (size_t)N_NODES * sizeof(int);
    int* rank    = (int*)ws;         ws += (size_t)ETOT * sizeof(int);
    unsigned short* sorted16 = (unsigned short*)ws;   // ETOT u16

    // W fragments (all layers) + CSR by dst + degree-sort perm (shared by all layers)
    wfrag_kernel<<<48, 256, 0, stream>>>(Wl, Wr, Wfrag);
    (void)hipMemsetAsync(counts, 0, (size_t)N_NODES * sizeof(int), stream);
    rank_hist_kernel<<<(ETOT + 255) / 256, 256, 0, stream>>>(ei, counts, rank);
    scan1_kernel<<<SCAN_BLOCKS, 1024, 0, stream>>>(counts, offsets, bsum);
    scan2_kernel<<<1, 64, 0, stream>>>(bsum, bpre);
    scan3_kernel<<<SCAN_BLOCKS, 1024, 0, stream>>>(offsets, bpre);
    scatter_kernel<<<(ETOT + 255) / 256, 256, 0, stream>>>(ei, offsets, rank, sorted16);
    deg_hist_kernel<<<SCAN_BLOCKS, 1024, 0, stream>>>(counts, blockhist);
    deg_scan_kernel<<<1, 256, 0, stream>>>(blockhist);
    deg_scatter_kernel<<<SCAN_BLOCKS, 1024, 0, stream>>>(counts, blockhist, perm);

    int gat_waves  = (N_NODES + 3) / 4;                       // 4 nodes / wave
    int gat_blocks = (gat_waves * 64 + 255) / 256;            // 3125
    for (int l = 0; l < L; ++l) {
        const float* hin = (l == 0) ? x : h;
        gemm_mfma_kernel<<<(N_NODES + 63) / 64, 256, 0, stream>>>(
            hin, Wfrag + (size_t)l * 4096 * 8, xlh, xrh);
        gat_node_kernel<<<gat_blocks, 256, 0, stream>>>(
            xlh, xrh, offsets, sorted16, perm,
            att + (size_t)l * D, bias + (size_t)l * D,
            gamma + (size_t)l * D, beta + (size_t)l * D, hin, h);
    }
}